// Round 1
// baseline (329.677 us; speedup 1.0000x reference)
//
#include <hip/hip_runtime.h>

// ProbSparseAttention (actually full MHA): out = softmax((XWq)(XWk)^T/8)(XWv) Wo
// B=2, L=2048, D=1024, H=16, dk=64. fp32 in/out, fp16 MFMA internally.

typedef _Float16 h16;
typedef _Float16 half8 __attribute__((ext_vector_type(8)));
typedef _Float16 half4 __attribute__((ext_vector_type(4)));
typedef float f32x4 __attribute__((ext_vector_type(4)));

#define D_MODEL 1024
#define N_HEADS 16
#define D_HEAD  64
#define SEQ_L   2048
#define NBATCH  2

// ---------------------------------------------------------------------------
// GEMM: C[M=4096, N=1024] = A[4096,1024] @ W[1024,1024] + bias
// 128x128 tile, BK=32, 4 waves (2x2), mfma_f32_16x16x32_f16.
// LDS layouts (both [row][32 f16] = 64B rows, XOR swizzle on byte bits 4-5):
//   As[m][k], Bs[n][k] (W transposed during staging) -> ds_read_b128 frags.
// Fragment maps: A/B: k = (lane>>4)*8+e (same map both operands => safe).
// C/D (HW-verified): col = lane&15, row = (lane>>4)*4 + reg.
// ---------------------------------------------------------------------------
template <bool A_F16, bool OUT_PROJ>
__device__ __forceinline__ void gemm_body(const float* __restrict__ Af,
                                          const h16* __restrict__ Ah,
                                          const float* __restrict__ W,
                                          const float* __restrict__ bias,
                                          h16* __restrict__ out_h,
                                          float* __restrict__ out_f) {
  __shared__ __align__(16) char smem[16384];
  char* As = smem;         // 128 rows * 64B
  char* Bs = smem + 8192;  // 128 rows * 64B
  const int tid = threadIdx.x;
  const int lane = tid & 63;
  const int w = tid >> 6;
  const int wm = w >> 1, wn = w & 1;
  const int m0 = blockIdx.x * 128;
  const int n0 = blockIdx.y * 128;
  const int K = 1024, N = 1024;
  const int cl = lane & 15, s = lane >> 4;

  const f32x4 zero = {0.0f, 0.0f, 0.0f, 0.0f};
  f32x4 acc[4][4];
#pragma unroll
  for (int i = 0; i < 4; i++)
#pragma unroll
    for (int j = 0; j < 4; j++) acc[i][j] = zero;

  for (int k0 = 0; k0 < K; k0 += 32) {
    // ---- stage A tile (128 x 32) ----
    if (A_F16) {
#pragma unroll
      for (int p = 0; p < 2; p++) {
        int fi = p * 256 + tid;
        int r = fi >> 2, g = fi & 3;  // granule of 8 halves
        half8 v = *reinterpret_cast<const half8*>(Ah + (size_t)(m0 + r) * K + k0 + g * 8);
        int swz = ((r >> 1) & 3) << 4;
        *reinterpret_cast<half8*>(As + r * 64 + ((g * 16) ^ swz)) = v;
      }
    } else {
#pragma unroll
      for (int p = 0; p < 4; p++) {
        int fi = p * 256 + tid;
        int r = fi >> 3, c4 = fi & 7;  // 4 f32 -> 4 f16
        float4 v = *reinterpret_cast<const float4*>(Af + (size_t)(m0 + r) * K + k0 + c4 * 4);
        half4 hv = {(h16)v.x, (h16)v.y, (h16)v.z, (h16)v.w};
        int swz = ((r >> 1) & 3) << 4;
        *reinterpret_cast<half4*>(As + r * 64 + ((c4 * 8) ^ swz)) = hv;
      }
    }
    // ---- stage B tile: W[k0+kk][n0+n] f32 -> Bs[n][kk] f16 (transpose) ----
#pragma unroll
    for (int p = 0; p < 4; p++) {
      int fi = p * 256 + tid;
      int kk = fi >> 5, n4 = fi & 31;
      float4 v = *reinterpret_cast<const float4*>(W + (size_t)(k0 + kk) * N + n0 + n4 * 4);
      float vv[4] = {v.x, v.y, v.z, v.w};
#pragma unroll
      for (int j = 0; j < 4; j++) {
        int n = n4 * 4 + j;
        int swz = ((n >> 1) & 3) << 4;
        *reinterpret_cast<h16*>(Bs + n * 64 + ((kk * 2) ^ swz)) = (h16)vv[j];
      }
    }
    __syncthreads();
    // ---- compute: 16 MFMAs ----
    half8 afr[4], bfr[4];
#pragma unroll
    for (int i = 0; i < 4; i++) {
      int r = wm * 64 + i * 16 + cl;
      int swz = ((r >> 1) & 3) << 4;
      afr[i] = *reinterpret_cast<const half8*>(As + r * 64 + ((s * 16) ^ swz));
    }
#pragma unroll
    for (int j = 0; j < 4; j++) {
      int n = wn * 64 + j * 16 + cl;
      int swz = ((n >> 1) & 3) << 4;
      bfr[j] = *reinterpret_cast<const half8*>(Bs + n * 64 + ((s * 16) ^ swz));
    }
#pragma unroll
    for (int i = 0; i < 4; i++)
#pragma unroll
      for (int j = 0; j < 4; j++)
        acc[i][j] = __builtin_amdgcn_mfma_f32_16x16x32_f16(afr[i], bfr[j], acc[i][j], 0, 0, 0);
    __syncthreads();
  }

  // ---- epilogue ----
#pragma unroll
  for (int i = 0; i < 4; i++)
#pragma unroll
    for (int j = 0; j < 4; j++) {
      int c = n0 + wn * 64 + j * 16 + cl;
      float bv = bias[c];
      int rbase = m0 + wm * 64 + i * 16 + s * 4;
#pragma unroll
      for (int reg = 0; reg < 4; reg++) {
        int m = rbase + reg;
        float val = acc[i][j][reg] + bv;
        if (OUT_PROJ) {
          // write f16 in [B, H, L, dk] layout for the attention kernel
          int b = m >> 11, l = m & 2047;
          int h = c >> 6, d = c & 63;
          out_h[((size_t)(b * N_HEADS + h) * SEQ_L + l) * D_HEAD + d] = (h16)val;
        } else {
          out_f[(size_t)m * D_MODEL + c] = val;
        }
      }
    }
}

struct ProjArgs {
  const float* A[3];
  const float* W[3];
  const float* b[3];
  h16* out[3];
};

__global__ __launch_bounds__(256) void proj_kernel(ProjArgs pa) {
  int z = blockIdx.z;
  gemm_body<false, true>(pa.A[z], nullptr, pa.W[z], pa.b[z], pa.out[z], nullptr);
}

__global__ __launch_bounds__(256) void out_kernel(const h16* __restrict__ A,
                                                  const float* __restrict__ W,
                                                  const float* __restrict__ b,
                                                  float* __restrict__ out) {
  gemm_body<true, false>(nullptr, A, W, b, nullptr, out);
}

// ---------------------------------------------------------------------------
// Flash attention. grid (32 qtiles, 32 b*h). 256 threads = 4 waves.
// Wave w owns 16 q rows (q0 = qt*64 + w*16). KV tile = 128.
// Ks [128 kv][64 d]  (natural layout == B-operand of QK^T), swizzled
// Vs [64 d][128 kv]  (transposed during staging == B-operand of PV), swizzled
// Pw per-wave [16 q][128 kv] f16 (A-operand of PV), swizzled
// ---------------------------------------------------------------------------
__global__ __launch_bounds__(256) void attn_kernel(const h16* __restrict__ Qp,
                                                   const h16* __restrict__ Kp,
                                                   const h16* __restrict__ Vp,
                                                   h16* __restrict__ ctx) {
  __shared__ __align__(16) char smem[49152];
  char* Ks = smem;           // 128 rows * 128B
  char* Vs = smem + 16384;   // 64 rows * 256B
  char* Ps = smem + 32768;   // 4 waves * 16 rows * 256B
  const int tid = threadIdx.x;
  const int lane = tid & 63;
  const int w = tid >> 6;
  char* Pw = Ps + w * 4096;
  const int qt = blockIdx.x;
  const int bh = blockIdx.y;
  const size_t base = (size_t)bh * SEQ_L * D_HEAD;
  const int q0 = qt * 64 + w * 16;
  const int cl = lane & 15, s = lane >> 4;

  // hoist q fragments (A-operand rows q0+cl, k = 32*kk + s*8 + e)
  half8 qf[2];
#pragma unroll
  for (int kk = 0; kk < 2; kk++)
    qf[kk] = *reinterpret_cast<const half8*>(Qp + base + (size_t)(q0 + cl) * D_HEAD + kk * 32 + s * 8);

  const f32x4 zero = {0.0f, 0.0f, 0.0f, 0.0f};
  f32x4 acc[4];
#pragma unroll
  for (int t = 0; t < 4; t++) acc[t] = zero;
  float mrow[4] = {-INFINITY, -INFINITY, -INFINITY, -INFINITY};
  float lrow[4] = {0.f, 0.f, 0.f, 0.f};

  for (int kv0 = 0; kv0 < SEQ_L; kv0 += 128) {
    // ---- stage K tile: rows kv, 8 granules of 8 halves ----
#pragma unroll
    for (int p = 0; p < 4; p++) {
      int fi = p * 256 + tid;
      int r = fi >> 3, g = fi & 7;
      half8 v = *reinterpret_cast<const half8*>(Kp + base + (size_t)(kv0 + r) * D_HEAD + g * 8);
      *reinterpret_cast<half8*>(Ks + r * 128 + ((g ^ (r & 7)) * 16)) = v;
    }
    // ---- stage V transposed: Vp[kv][d] -> Vs[d][kv] ----
#pragma unroll
    for (int p = 0; p < 4; p++) {
      int fi = p * 256 + tid;
      int r = fi >> 3, dg = fi & 7;
      half8 v = *reinterpret_cast<const half8*>(Vp + base + (size_t)(kv0 + r) * D_HEAD + dg * 8);
#pragma unroll
      for (int j = 0; j < 8; j++) {
        int d = dg * 8 + j;
        *reinterpret_cast<h16*>(Vs + d * 256 + ((r * 2) ^ ((d & 7) << 4))) = v[j];
      }
    }
    __syncthreads();

    // ---- QK^T: S[16 q][128 kv], 8 col-tiles x 2 k-steps ----
    f32x4 sc[8];
#pragma unroll
    for (int t = 0; t < 8; t++) {
      sc[t] = zero;
#pragma unroll
      for (int kk = 0; kk < 2; kk++) {
        int r = t * 16 + cl;
        int g = (kk * 4 + s) ^ (r & 7);
        half8 bf = *reinterpret_cast<const half8*>(Ks + r * 128 + g * 16);
        sc[t] = __builtin_amdgcn_mfma_f32_16x16x32_f16(qf[kk], bf, sc[t], 0, 0, 0);
      }
    }

    // ---- online softmax (row = s*4+reg; row-reduce = 16-lane shfl_xor) ----
    float mloc[4];
#pragma unroll
    for (int rg = 0; rg < 4; rg++) mloc[rg] = -INFINITY;
#pragma unroll
    for (int t = 0; t < 8; t++)
#pragma unroll
      for (int rg = 0; rg < 4; rg++) {
        sc[t][rg] *= 0.125f;  // 1/sqrt(dk)
        mloc[rg] = fmaxf(mloc[rg], sc[t][rg]);
      }
    float rsum[4];
#pragma unroll
    for (int rg = 0; rg < 4; rg++) {
#pragma unroll
      for (int msk = 1; msk < 16; msk <<= 1)
        mloc[rg] = fmaxf(mloc[rg], __shfl_xor(mloc[rg], msk));
      float mnew = fmaxf(mrow[rg], mloc[rg]);
      float alpha = __expf(mrow[rg] - mnew);
      mrow[rg] = mnew;
      lrow[rg] *= alpha;
#pragma unroll
      for (int td = 0; td < 4; td++) acc[td][rg] *= alpha;
      rsum[rg] = 0.f;
    }
#pragma unroll
    for (int t = 0; t < 8; t++)
#pragma unroll
      for (int rg = 0; rg < 4; rg++) {
        float p = __expf(sc[t][rg] - mrow[rg]);
        rsum[rg] += p;
        int pr = s * 4 + rg;
        int pc = t * 16 + cl;
        *reinterpret_cast<h16*>(Pw + pr * 256 + ((pc * 2) ^ ((pr & 7) << 4))) = (h16)p;
      }
#pragma unroll
    for (int rg = 0; rg < 4; rg++) {
#pragma unroll
      for (int msk = 1; msk < 16; msk <<= 1) rsum[rg] += __shfl_xor(rsum[rg], msk);
      lrow[rg] += rsum[rg];
    }

    // ---- PV: acc[16 q][64 d] += P[16 x 128] @ V[128 x 64] ----
#pragma unroll
    for (int kvs = 0; kvs < 4; kvs++) {
      int pg = (kvs * 4 + s) ^ (cl & 7);
      half8 pf = *reinterpret_cast<const half8*>(Pw + cl * 256 + pg * 16);
#pragma unroll
      for (int td = 0; td < 4; td++) {
        int d = td * 16 + cl;
        int vg = (kvs * 4 + s) ^ (d & 7);
        half8 vf = *reinterpret_cast<const half8*>(Vs + d * 256 + vg * 16);
        acc[td] = __builtin_amdgcn_mfma_f32_16x16x32_f16(pf, vf, acc[td], 0, 0, 0);
      }
    }
    __syncthreads();
  }

  // ---- write ctx as [B, L, H*dk] f16 for the output GEMM ----
  int b = bh >> 4, h = bh & 15;
#pragma unroll
  for (int td = 0; td < 4; td++)
#pragma unroll
    for (int rg = 0; rg < 4; rg++) {
      int qrow = q0 + s * 4 + rg;
      int d = td * 16 + cl;
      float v = acc[td][rg] / lrow[rg];
      ctx[((size_t)b * SEQ_L + qrow) * D_MODEL + h * D_HEAD + d] = (h16)v;
    }
}

// ---------------------------------------------------------------------------
extern "C" void kernel_launch(void* const* d_in, const int* in_sizes, int n_in,
                              void* d_out, int out_size, void* d_ws, size_t ws_size,
                              hipStream_t stream) {
  const float* Q = (const float*)d_in[0];
  const float* K = (const float*)d_in[1];
  const float* V = (const float*)d_in[2];
  const float* Wq = (const float*)d_in[3];
  const float* bq = (const float*)d_in[4];
  const float* Wk = (const float*)d_in[5];
  const float* bk = (const float*)d_in[6];
  const float* Wv = (const float*)d_in[7];
  const float* bv = (const float*)d_in[8];
  const float* Wo = (const float*)d_in[9];
  const float* bo = (const float*)d_in[10];
  float* out = (float*)d_out;

  const size_t NE = (size_t)NBATCH * SEQ_L * D_MODEL;  // 4M elements
  h16* qp = (h16*)d_ws;
  h16* kp = qp + NE;
  h16* vp = kp + NE;
  h16* ctx = vp + NE;  // total 32 MB of ws

  ProjArgs pa;
  pa.A[0] = Q;  pa.A[1] = K;  pa.A[2] = V;
  pa.W[0] = Wq; pa.W[1] = Wk; pa.W[2] = Wv;
  pa.b[0] = bq; pa.b[1] = bk; pa.b[2] = bv;
  pa.out[0] = qp; pa.out[1] = kp; pa.out[2] = vp;

  proj_kernel<<<dim3(32, 8, 3), 256, 0, stream>>>(pa);
  attn_kernel<<<dim3(32, 32), 256, 0, stream>>>(qp, kp, vp, ctx);
  out_kernel<<<dim3(32, 8), 256, 0, stream>>>(ctx, Wo, bo, out);
}

// Round 3
// 247.373 us; speedup vs baseline: 1.3327x; 1.3327x over previous
//
#include <hip/hip_runtime.h>

// MHA: out = softmax((XWq)(XWk)^T/8)(XWv) Wo ; B=2, L=2048, D=1024, H=16, dk=64
// fp32 in/out, f16 MFMA internally, f32 accumulation.

typedef _Float16 h16;
typedef _Float16 half8 __attribute__((ext_vector_type(8)));
typedef _Float16 half4 __attribute__((ext_vector_type(4)));
typedef float f32x4 __attribute__((ext_vector_type(4)));

#define D_MODEL 1024
#define N_HEADS 16
#define D_HEAD  64
#define SEQ_L   2048
#define NBATCH  2
#define MTOT    4096  // B*L
// fold 1/sqrt(dk) and log2(e) into Wq so scores are in exp2 units
#define QSCALE  0.18033688011f

// async global->LDS, 16B per lane, wave-uniform LDS base (HW adds lane*16)
#define GLD16(gp, lp)                                                  \
  __builtin_amdgcn_global_load_lds(                                    \
      (const __attribute__((address_space(1))) void*)(gp),             \
      (__attribute__((address_space(3))) void*)(lp), 16, 0, 0)

// ---------------------------------------------------------------------------
// conversion kernels
// ---------------------------------------------------------------------------
struct XArgs { const float* src[3]; h16* dst[3]; };

__global__ __launch_bounds__(256) void convert_x(XArgs xa) {
  const float* src = xa.src[blockIdx.y];
  h16* dst = xa.dst[blockIdx.y];
  size_t i = ((size_t)blockIdx.x * 256 + threadIdx.x) * 8;
  float4 a = *reinterpret_cast<const float4*>(src + i);
  float4 b = *reinterpret_cast<const float4*>(src + i + 4);
  half8 o = {(h16)a.x, (h16)a.y, (h16)a.z, (h16)a.w,
             (h16)b.x, (h16)b.y, (h16)b.z, (h16)b.w};
  *reinterpret_cast<half8*>(dst + i) = o;
}

struct WArgs { const float* w[4]; h16* wt[4]; };

__global__ __launch_bounds__(256) void convert_wt(WArgs wa) {
  int z = blockIdx.z;
  const float* W = wa.w[z];
  h16* Wt = wa.wt[z];
  float scale = (z == 0) ? QSCALE : 1.0f;
  int k0 = blockIdx.x * 64, n0 = blockIdx.y * 64;
  __shared__ h16 T[64][65];
  int tid = threadIdx.x;
  // stage 64(k) x 64(n) tile, transposed into T[n][k]: 1024 float4 items
#pragma unroll
  for (int q = 0; q < 4; q++) {
    int fi = q * 256 + tid;
    int r = fi >> 4, c4 = (fi & 15) * 4;  // r: k-row, c4: n-col
    float4 v = *reinterpret_cast<const float4*>(W + (size_t)(k0 + r) * D_MODEL + n0 + c4);
    T[c4 + 0][r] = (h16)(v.x * scale);
    T[c4 + 1][r] = (h16)(v.y * scale);
    T[c4 + 2][r] = (h16)(v.z * scale);
    T[c4 + 3][r] = (h16)(v.w * scale);
  }
  __syncthreads();
  // write back: 64 n-rows x 8 k-granules = 512 items (q < 2 !)
#pragma unroll
  for (int q = 0; q < 2; q++) {
    int fi = q * 256 + tid;
    int r = fi >> 3, g = fi & 7;  // r: n-row, g: k granule of 8
    half8 o;
#pragma unroll
    for (int j = 0; j < 8; j++) o[j] = T[r][g * 8 + j];
    *reinterpret_cast<half8*>(Wt + (size_t)(n0 + r) * D_MODEL + k0 + g * 8) = o;
  }
}

__global__ __launch_bounds__(256) void convert_bq(const float* bq, float* bqs) {
  int i = blockIdx.x * 256 + threadIdx.x;
  if (i < D_MODEL) bqs[i] = bq[i] * QSCALE;
}

// ---------------------------------------------------------------------------
// f16 GEMM, m97 structure: 128x128 tile, BK=32, global_load_lds x16B,
// linear LDS [r][32] (64B rows -> reads at bank floor), 4 waves (2x2).
// mode 0: out f16 natural [m][n]; mode 1: out f16 transposed per-head
// [b][h][d][L] (half4 along L); mode 2: out f32 natural.
// ---------------------------------------------------------------------------
__global__ __launch_bounds__(256) void gemm_f16(const h16* __restrict__ A,
                                                const h16* __restrict__ Bt,
                                                const float* __restrict__ bias,
                                                h16* __restrict__ outh,
                                                float* __restrict__ outf,
                                                int mode) {
  __shared__ __align__(16) h16 As[128 * 32];
  __shared__ __align__(16) h16 Bs[128 * 32];
  const int tid = threadIdx.x;
  const int lane = tid & 63;
  const int w = tid >> 6;
  const int wm = w >> 1, wn = w & 1;
  const int cl = lane & 15, s = lane >> 4;
  const int m0 = blockIdx.x * 128;
  const int n0 = blockIdx.y * 128;
  const int lr = lane >> 2, lg = lane & 3;  // staging: row-in-16, 16B granule

  const f32x4 zero = {0.f, 0.f, 0.f, 0.f};
  f32x4 acc[4][4];
#pragma unroll
  for (int i = 0; i < 4; i++)
#pragma unroll
    for (int j = 0; j < 4; j++) acc[i][j] = zero;

  const h16* aw = A + (size_t)(m0 + w * 32) * D_MODEL;
  const h16* bw = Bt + (size_t)(n0 + w * 32) * D_MODEL;

  for (int k0 = 0; k0 < D_MODEL; k0 += 32) {
#pragma unroll
    for (int issue = 0; issue < 2; issue++) {
      GLD16(aw + (size_t)(issue * 16 + lr) * D_MODEL + k0 + lg * 8,
            As + (w * 32 + issue * 16) * 32);
      GLD16(bw + (size_t)(issue * 16 + lr) * D_MODEL + k0 + lg * 8,
            Bs + (w * 32 + issue * 16) * 32);
    }
    __syncthreads();
    half8 af[4], bf[4];
#pragma unroll
    for (int i = 0; i < 4; i++)
      af[i] = *reinterpret_cast<const half8*>(As + (wm * 64 + i * 16 + cl) * 32 + s * 8);
#pragma unroll
    for (int j = 0; j < 4; j++)
      bf[j] = *reinterpret_cast<const half8*>(Bs + (wn * 64 + j * 16 + cl) * 32 + s * 8);
#pragma unroll
    for (int i = 0; i < 4; i++)
#pragma unroll
      for (int j = 0; j < 4; j++)
        acc[i][j] = __builtin_amdgcn_mfma_f32_16x16x32_f16(af[i], bf[j], acc[i][j], 0, 0, 0);
    __syncthreads();
  }

#pragma unroll
  for (int i = 0; i < 4; i++)
#pragma unroll
    for (int j = 0; j < 4; j++) {
      int c = n0 + wn * 64 + j * 16 + cl;
      float bv = bias[c];
      int mb = m0 + wm * 64 + i * 16 + s * 4;
      if (mode == 0) {
#pragma unroll
        for (int r = 0; r < 4; r++)
          outh[(size_t)(mb + r) * D_MODEL + c] = (h16)(acc[i][j][r] + bv);
      } else if (mode == 1) {
        // [b][h][d][L]: 4 regs are consecutive L -> half4
        int b = mb >> 11, l = mb & 2047;
        int h = c >> 6, d = c & 63;
        half4 o = {(h16)(acc[i][j][0] + bv), (h16)(acc[i][j][1] + bv),
                   (h16)(acc[i][j][2] + bv), (h16)(acc[i][j][3] + bv)};
        *reinterpret_cast<half4*>(outh + (((size_t)(b * N_HEADS + h) * D_HEAD + d) * SEQ_L + l)) = o;
      } else {
#pragma unroll
        for (int r = 0; r < 4; r++)
          outf[(size_t)(mb + r) * D_MODEL + c] = acc[i][j][r] + bv;
      }
    }
}

// ---------------------------------------------------------------------------
// Flash attention. grid (16 qtiles, 32 b*h). 256 thr = 4 waves, 32 q-rows/wave.
// KVBLK=128. Ks [128 kv][64 d], Vs = V^T [64 d][128 kv] (staged coalesced from
// global V^T), Ps per-wave [32 q][128 kv]. All LDS rows XOR-swizzled.
// Scores arrive pre-scaled in exp2 units (scale folded into Wq).
// ---------------------------------------------------------------------------
__global__ __launch_bounds__(256) void attn_kernel(const h16* __restrict__ Qh,
                                                   const h16* __restrict__ Kh,
                                                   const h16* __restrict__ Vt,
                                                   h16* __restrict__ ctx) {
  __shared__ __align__(16) char smem[65536];
  char* Ks = smem;           // 128 rows * 128B
  char* Vs = smem + 16384;   // 64 rows * 256B
  char* Ps = smem + 32768;   // 4 waves * 32 rows * 256B
  const int tid = threadIdx.x;
  const int lane = tid & 63;
  const int w = tid >> 6;
  char* Pw = Ps + w * 8192;
  const int qt = blockIdx.x;
  const int bh = blockIdx.y;
  const int b = bh >> 4, h = bh & 15;
  const int q0 = qt * 128 + w * 32;
  const int cl = lane & 15, s = lane >> 4;

  // hoist Q fragments: rows q0+qr*16+cl, k granule kk*32 + s*8
  half8 qf[2][2];
#pragma unroll
  for (int qr = 0; qr < 2; qr++)
#pragma unroll
    for (int kk = 0; kk < 2; kk++)
      qf[qr][kk] = *reinterpret_cast<const half8*>(
          Qh + (size_t)(b * SEQ_L + q0 + qr * 16 + cl) * D_MODEL + h * D_HEAD + kk * 32 + s * 8);

  const f32x4 zero = {0.f, 0.f, 0.f, 0.f};
  f32x4 acc[2][4];
#pragma unroll
  for (int qr = 0; qr < 2; qr++)
#pragma unroll
    for (int td = 0; td < 4; td++) acc[qr][td] = zero;
  float mrow[2][4], lrow[2][4];
#pragma unroll
  for (int qr = 0; qr < 2; qr++)
#pragma unroll
    for (int rg = 0; rg < 4; rg++) { mrow[qr][rg] = -INFINITY; lrow[qr][rg] = 0.f; }

  for (int kv0 = 0; kv0 < SEQ_L; kv0 += 128) {
    // ---- stage K [128][64]: vector half8, swizzled granule ----
#pragma unroll
    for (int p = 0; p < 4; p++) {
      int fi = p * 256 + tid;
      int r = fi >> 3, g = fi & 7;
      half8 v = *reinterpret_cast<const half8*>(
          Kh + (size_t)(b * SEQ_L + kv0 + r) * D_MODEL + h * D_HEAD + g * 8);
      *reinterpret_cast<half8*>(Ks + r * 128 + ((g ^ (r & 7)) << 4)) = v;
    }
    // ---- stage V^T [64][128]: rows contiguous in global, swizzled ----
#pragma unroll
    for (int p = 0; p < 4; p++) {
      int fi = p * 256 + tid;
      int r = fi >> 4, g = fi & 15;
      half8 v = *reinterpret_cast<const half8*>(
          Vt + ((size_t)bh * D_HEAD + r) * SEQ_L + kv0 + g * 8);
      *reinterpret_cast<half8*>(Vs + r * 256 + ((g ^ (r & 7)) << 4)) = v;
    }
    __syncthreads();

    // ---- QK^T: S[32 q][128 kv]; bf shared across the two q-frags ----
    f32x4 sc[2][8];
#pragma unroll
    for (int t = 0; t < 8; t++) {
      sc[0][t] = zero;
      sc[1][t] = zero;
#pragma unroll
      for (int kk = 0; kk < 2; kk++) {
        int r = t * 16 + cl;
        half8 bf = *reinterpret_cast<const half8*>(Ks + r * 128 + (((kk * 4 + s) ^ (cl & 7)) << 4));
        sc[0][t] = __builtin_amdgcn_mfma_f32_16x16x32_f16(qf[0][kk], bf, sc[0][t], 0, 0, 0);
        sc[1][t] = __builtin_amdgcn_mfma_f32_16x16x32_f16(qf[1][kk], bf, sc[1][t], 0, 0, 0);
      }
    }

    // ---- online softmax in exp2 units (row = qr*16 + s*4 + rg) ----
#pragma unroll
    for (int qr = 0; qr < 2; qr++)
#pragma unroll
      for (int rg = 0; rg < 4; rg++) {
        float ml = sc[qr][0][rg];
#pragma unroll
        for (int t = 1; t < 8; t++) ml = fmaxf(ml, sc[qr][t][rg]);
#pragma unroll
        for (int msk = 1; msk < 16; msk <<= 1) ml = fmaxf(ml, __shfl_xor(ml, msk));
        float mn = fmaxf(mrow[qr][rg], ml);
        float al = exp2f(mrow[qr][rg] - mn);
        mrow[qr][rg] = mn;
        lrow[qr][rg] *= al;
#pragma unroll
        for (int td = 0; td < 4; td++) acc[qr][td][rg] *= al;
        float rs = 0.f;
        int pr = qr * 16 + s * 4 + rg;
        int swz = ((s & 3) << 5) ^ ((rg & 1) << 7);
#pragma unroll
        for (int t = 0; t < 8; t++) {
          float p = exp2f(sc[qr][t][rg] - mn);
          rs += p;
          int pc = t * 16 + cl;
          *reinterpret_cast<h16*>(Pw + pr * 256 + ((pc * 2) ^ swz)) = (h16)p;
        }
#pragma unroll
        for (int msk = 1; msk < 16; msk <<= 1) rs += __shfl_xor(rs, msk);
        lrow[qr][rg] += rs;
      }

    // ---- PV: acc[32 q][64 d] += P[32x128] @ V[128x64] ----
#pragma unroll
    for (int kvs = 0; kvs < 4; kvs++) {
      half8 pf[2];
#pragma unroll
      for (int qr = 0; qr < 2; qr++) {
        int pr = qr * 16 + cl;
        pf[qr] = *reinterpret_cast<const half8*>(
            Pw + pr * 256 + ((((kvs * 4 + s) << 4) ^ (((pr >> 2) & 3) << 5)) ^ ((pr & 1) << 7)));
      }
#pragma unroll
      for (int td = 0; td < 4; td++) {
        int d = td * 16 + cl;
        half8 vf = *reinterpret_cast<const half8*>(Vs + d * 256 + (((kvs * 4 + s) ^ (d & 7)) << 4));
        acc[0][td] = __builtin_amdgcn_mfma_f32_16x16x32_f16(pf[0], vf, acc[0][td], 0, 0, 0);
        acc[1][td] = __builtin_amdgcn_mfma_f32_16x16x32_f16(pf[1], vf, acc[1][td], 0, 0, 0);
      }
    }
    __syncthreads();
  }

  // ---- write ctx f16 natural [b*L + q][h*64 + d] ----
#pragma unroll
  for (int qr = 0; qr < 2; qr++)
#pragma unroll
    for (int td = 0; td < 4; td++)
#pragma unroll
      for (int rg = 0; rg < 4; rg++) {
        int row = q0 + qr * 16 + s * 4 + rg;
        int d = td * 16 + cl;
        float v = acc[qr][td][rg] / lrow[qr][rg];
        ctx[(size_t)(b * SEQ_L + row) * D_MODEL + h * D_HEAD + d] = (h16)v;
      }
}

// ---------------------------------------------------------------------------
extern "C" void kernel_launch(void* const* d_in, const int* in_sizes, int n_in,
                              void* d_out, int out_size, void* d_ws, size_t ws_size,
                              hipStream_t stream) {
  const float* Q = (const float*)d_in[0];
  const float* K = (const float*)d_in[1];
  const float* V = (const float*)d_in[2];
  const float* Wq = (const float*)d_in[3];
  const float* bq = (const float*)d_in[4];
  const float* Wk = (const float*)d_in[5];
  const float* bk = (const float*)d_in[6];
  const float* Wv = (const float*)d_in[7];
  const float* bv = (const float*)d_in[8];
  const float* Wo = (const float*)d_in[9];
  const float* bo = (const float*)d_in[10];
  float* out = (float*)d_out;

  char* ws = (char*)d_ws;
  const size_t MB = 1024 * 1024;
  h16* Xh[3] = {(h16*)(ws), (h16*)(ws + 8 * MB), (h16*)(ws + 16 * MB)};
  h16* Wt[4] = {(h16*)(ws + 24 * MB), (h16*)(ws + 26 * MB),
                (h16*)(ws + 28 * MB), (h16*)(ws + 30 * MB)};
  h16* Qh = (h16*)(ws + 32 * MB);
  h16* Kh = (h16*)(ws + 40 * MB);
  h16* Vt = (h16*)(ws + 48 * MB);
  float* bqs = (float*)(ws + 56 * MB);
  h16* ctx = Xh[0];  // Xh[0] dead after projections

  XArgs xa;
  xa.src[0] = Q; xa.src[1] = K; xa.src[2] = V;
  xa.dst[0] = Xh[0]; xa.dst[1] = Xh[1]; xa.dst[2] = Xh[2];
  convert_x<<<dim3(2048, 3), 256, 0, stream>>>(xa);

  WArgs wa;
  wa.w[0] = Wq; wa.w[1] = Wk; wa.w[2] = Wv; wa.w[3] = Wo;
  wa.wt[0] = Wt[0]; wa.wt[1] = Wt[1]; wa.wt[2] = Wt[2]; wa.wt[3] = Wt[3];
  convert_wt<<<dim3(16, 16, 4), 256, 0, stream>>>(wa);
  convert_bq<<<dim3(4), 256, 0, stream>>>(bq, bqs);

  // projections: z=0 Q (natural), z=1 K (natural), z=2 V (transposed per head)
  gemm_f16<<<dim3(32, 8), 256, 0, stream>>>(Xh[0], Wt[0], bqs, Qh, nullptr, 0);
  gemm_f16<<<dim3(32, 8), 256, 0, stream>>>(Xh[1], Wt[1], bk, Kh, nullptr, 0);
  gemm_f16<<<dim3(32, 8), 256, 0, stream>>>(Xh[2], Wt[2], bv, Vt, nullptr, 1);

  attn_kernel<<<dim3(16, 32), 256, 0, stream>>>(Qh, Kh, Vt, ctx);

  gemm_f16<<<dim3(32, 8), 256, 0, stream>>>(ctx, Wt[3], bo, nullptr, out, 2);
}